// Round 1
// 7124.637 us; speedup vs baseline: 1.2227x; 1.2227x over previous
//
#include <hip/hip_runtime.h>
#include <math.h>

typedef unsigned long long ull;

// LTC liquid scan — batch-amortized GEMM decomposition.
// Grid 256 = 16 batch-tiles x 16 neuron-tiles; block 512 threads, 1 block/CU
// (grid==CU count => co-residency => spin-wait is safe).
// W_rec slice [32 n][512 k] = 64 KB in VGPRs (128/thread). W_in slice in LDS.
// Per-unfold cross-block state exchange x[8][512] via fence-free versioned
// 8-byte mailbox (RELAXED agent atomics only). 2 slots (jj parity).
//
// Round-4 change: ALL hot LDS rows are XOR-swizzled at float4 granularity
// (slot = g ^ ((g>>3)&7) within each row). The recurrent GEMV read had a
// 128-byte lane stride (kc*32 floats) => all 16 kc on one 4-bank group =
// 16-way conflict on every ds_read_b128; SQ_LDS_BANK_CONFLICT measured
// 1.67e9 (~31% of runtime). Swizzle spreads kc across all 8 bank groups
// (2 distinct addrs/group = free). Stage-writes become balanced 8/group
// (optimal for b128). wi/iro reads (were 2-group, 32-way) also fixed; the
// pitch-260 row stride contributes n mod 8 which combines with the XOR to
// cover all 8 groups. xsh pad (516) dropped -> rows 512, LDS 84->75.4 KB.

#define NN 512
#define FF 256
#define KK 6
#define BB 128
#define TT 256
#define BT 8         // batches per tile
#define NTL 32       // neurons per tile

#define XROW 512     // xsh row pitch (dwords); conflicts handled by swizzle
#define IPITCH 260   // = 65 float4
#define WIPITCH 260  // = 65 float4
#define PPITCH 17

#define DOT4(a, v) ((a).x * (v).x + (a).y * (v).y + (a).z * (v).z + (a).w * (v).w)

__global__ __launch_bounds__(512, 2) void liquid_kernel(
    const float* __restrict__ I,     // [B][T][F]
    const float* __restrict__ DT,    // [B][T]
    const float* __restrict__ Wrec,  // [N][N]
    const float* __restrict__ Win,   // [N][F]
    const float* __restrict__ bv, const float* __restrict__ Av,
    const float* __restrict__ tauv,
    ull* __restrict__ mbx,           // [16 bt][2 slot][8 b][512 n] versioned
    float* __restrict__ out)         // [B][T][N]
{
  __shared__ __align__(16) float lds[18856];  // 75.4 KB
  float* xsh = lds;                   // [8][512]  x_{jj-1}, swizzled f4 groups
  float* iro = lds + BT * XROW;       // [8][260]  input rows, swizzled
  float* wi  = iro + BT * IPITCH;     // [32][260] W_in slice, swizzled
  float* par = wi + NTL * WIPITCH;    // [256][17] k-chunk partials
  float* dts = par + 256 * PPITCH;    // [8] dt/K per batch

  const int blk = blockIdx.x;
  const int bt  = blk >> 4;          // batch tile
  const int nt  = blk & 15;          // neuron tile
  const int tid = threadIdx.x;
  const int kc  = tid & 15;          // k-chunk (32 k each)
  const int nq  = (tid >> 4) & 7;    // n-quad (4 n each)
  const int db  = tid >> 7;          // b-pair (2 b each)
  const int n0g = nt * NTL;          // global n base of this tile

  // ---- W_rec slice into VGPRs: wv[r][j] = Wrec[n0g+4nq+r][32kc+4j .. +3] ----
  float4 wv[4][8];
  #pragma unroll
  for (int r = 0; r < 4; ++r) {
    const float* wr = Wrec + (size_t)(n0g + nq * 4 + r) * NN + kc * 32;
    #pragma unroll
    for (int j = 0; j < 8; ++j) wv[r][j] = *(const float4*)(wr + 4 * j);
  }
  // ---- W_in slice into LDS (swizzled slot per float4 group) ----
  for (int idx = tid; idx < NTL * FF; idx += 512) {
    const int n = idx >> 8, f = idx & 255;
    const int g = f >> 2, gs = g ^ ((g >> 3) & 7);
    wi[n * WIPITCH + gs * 4 + (f & 3)] = Win[(size_t)(n0g + n) * FF + f];
  }
  // ---- per-neuron params + swizzled xo index for reduction threads ----
  float rA = 0.f, rIT = 0.f, rB = 0.f;
  int swn = 0;
  if (tid < 256) {
    const int rn = tid & 31;
    const int n = n0g + rn;
    rA = Av[n]; rIT = 1.0f / tauv[n]; rB = bv[n];
    const int gg = (n0g >> 2) + (rn >> 2);          // group of neuron n
    swn = ((gg ^ (nt & 7)) << 2) | (rn & 3);        // (gg>>3)&7 == nt&7
  }
  for (int idx = tid; idx < BT * XROW; idx += 512) xsh[idx] = 0.f;  // x0=0

  // ---- thread-constant swizzled addressing (hoisted out of the t-loop) ----
  const int lid = tid & 63;                         // lane in wave
  const int sb  = tid >> 6;                         // wave id / staging row
  const int gsi = lid ^ ((lid >> 3) & 7);           // iro stage-write slot
  const int sxr = (lid >> 2) & 7;                   // xsh stage swizzle sel
  const int sx  = kc & 7;                           // xsh GEMV read sel
  const int gb  = (kc * 4) ^ ((kc >> 1) & 7);       // wi/iro read slot base
  const float4* xq0 = (const float4*)xsh + (db * 2) * 128 + kc * 8;
  const float4* xq1 = xq0 + 128;
  const float4* iq0 = (const float4*)iro + (db * 2) * 65;
  const float4* iq1 = iq0 + 65;
  const float4* wq  = (const float4*)wi + (nq * 4) * 65;
  float4* xw = (float4*)xsh + sb * 128;             // stage-write row
  __syncthreads();

  int jj = 0;
  #pragma unroll 1
  for (int t = 0; t < TT; ++t) {
    // ---- stage input rows (swizzled) + dt ----
    ((float4*)iro)[sb * 65 + gsi] =
        *(const float4*)&I[((size_t)(bt * BT + sb) * TT + t) * FF + lid * 4];
    if (tid < BT) dts[tid] = DT[(size_t)(bt * BT + tid) * TT + t] * (1.0f / KK);
    __syncthreads();

    // ---- input GEMV partials: inp[b][n] over f in [16kc,16kc+16) ----
    {
      float ai0[4] = {0.f, 0.f, 0.f, 0.f}, ai1[4] = {0.f, 0.f, 0.f, 0.f};
      #pragma unroll
      for (int j2 = 0; j2 < 4; ++j2) {
        const int gg = gb ^ j2;                     // swizzled slot
        float4 w0 = wq[0 * 65 + gg];
        float4 w1 = wq[1 * 65 + gg];
        float4 w2 = wq[2 * 65 + gg];
        float4 w3 = wq[3 * 65 + gg];
        float4 xa = iq0[gg];
        float4 xb = iq1[gg];
        ai0[0] += DOT4(w0, xa); ai0[1] += DOT4(w1, xa);
        ai0[2] += DOT4(w2, xa); ai0[3] += DOT4(w3, xa);
        ai1[0] += DOT4(w0, xb); ai1[1] += DOT4(w1, xb);
        ai1[2] += DOT4(w2, xb); ai1[3] += DOT4(w3, xb);
      }
      #pragma unroll
      for (int r = 0; r < 4; ++r) {
        par[((db * 2 + 0) * NTL + nq * 4 + r) * PPITCH + kc] = ai0[r];
        par[((db * 2 + 1) * NTL + nq * 4 + r) * PPITCH + kc] = ai1[r];
      }
    }
    __syncthreads();
    float rInp = 0.f;
    if (tid < 256) {
      float s = rB;
      #pragma unroll
      for (int c = 0; c < 16; ++c) s += par[tid * PPITCH + c];
      rInp = s;
    }
    __syncthreads();  // par free for unfold reuse

    // ---- K unfolds ----
    #pragma unroll 1
    for (int kk = 0; kk < KK; ++kk) {
      ++jj;  // producing x_jj; consuming x_{jj-1}

      // stage x_{jj-1}[8][512] from mailbox (skip jj==1: x0=0 already in xsh)
      if (jj > 1) {
        const ull* src = mbx + (((size_t)bt * 2 + ((jj - 1) & 1)) << 12);
        const ull* p = src + sb * 512 + lid * 8;
        ull v[8];
        #pragma unroll
        for (int i = 0; i < 8; ++i)
          v[i] = __hip_atomic_load(p + i, __ATOMIC_RELAXED, __HIP_MEMORY_SCOPE_AGENT);
        #pragma unroll
        for (int i = 0; i < 8; ++i)
          while ((unsigned)(v[i] >> 32) != (unsigned)(jj - 1)) {
            __builtin_amdgcn_s_sleep(1);
            v[i] = __hip_atomic_load(p + i, __ATOMIC_RELAXED, __HIP_MEMORY_SCOPE_AGENT);
          }
        float4 fa, fb;
        fa.x = __uint_as_float((unsigned)v[0]);
        fa.y = __uint_as_float((unsigned)v[1]);
        fa.z = __uint_as_float((unsigned)v[2]);
        fa.w = __uint_as_float((unsigned)v[3]);
        fb.x = __uint_as_float((unsigned)v[4]);
        fb.y = __uint_as_float((unsigned)v[5]);
        fb.z = __uint_as_float((unsigned)v[6]);
        fb.w = __uint_as_float((unsigned)v[7]);
        const int g0 = 2 * lid;                     // logical groups 2l, 2l+1
        xw[g0 ^ sxr] = fa;
        xw[(g0 + 1) ^ sxr] = fb;
      }
      __syncthreads();

      // GEMV: acc[b][n] partial over k in [32kc, 32kc+32), W from VGPRs.
      // slot (j ^ sx) holds logical group j -> pairs with wv[r][j].
      {
        float acc0[4] = {0.f, 0.f, 0.f, 0.f}, acc1[4] = {0.f, 0.f, 0.f, 0.f};
        #pragma unroll
        for (int j = 0; j < 8; ++j) {
          float4 xv = xq0[j ^ sx];
          acc0[0] += DOT4(wv[0][j], xv); acc0[1] += DOT4(wv[1][j], xv);
          acc0[2] += DOT4(wv[2][j], xv); acc0[3] += DOT4(wv[3][j], xv);
        }
        #pragma unroll
        for (int j = 0; j < 8; ++j) {
          float4 xv = xq1[j ^ sx];
          acc1[0] += DOT4(wv[0][j], xv); acc1[1] += DOT4(wv[1][j], xv);
          acc1[2] += DOT4(wv[2][j], xv); acc1[3] += DOT4(wv[3][j], xv);
        }
        #pragma unroll
        for (int r = 0; r < 4; ++r) {
          par[((db * 2 + 0) * NTL + nq * 4 + r) * PPITCH + kc] = acc0[r];
          par[((db * 2 + 1) * NTL + nq * 4 + r) * PPITCH + kc] = acc1[r];
        }
      }
      __syncthreads();

      // reduce + nonlinearity + publish (+ output on last unfold)
      if (tid < 256) {
        float arg = rInp;
        #pragma unroll
        for (int c = 0; c < 16; ++c) arg += par[tid * PPITCH + c];
        const int rb = tid >> 5, rn = tid & 31;
        float f   = tanhf(arg);
        float dtk = dts[rb];
        float xo  = xsh[rb * XROW + swn];
        float xn  = fmaf(dtk * f, rA, xo) / fmaf(dtk, rIT + f, 1.0f);
        ull w = ((ull)(unsigned)jj << 32) | (ull)__float_as_uint(xn);
        __hip_atomic_store(mbx + (((size_t)bt * 2 + (jj & 1)) << 12) + rb * 512 + n0g + rn,
                           w, __ATOMIC_RELAXED, __HIP_MEMORY_SCOPE_AGENT);
        if (kk == KK - 1)
          out[((size_t)(bt * BT + rb) * TT + t) * NN + n0g + rn] = xn;
      }
      __syncthreads();  // xsh/par reads done before next stage overwrites
    }
  }
}

extern "C" void kernel_launch(void* const* d_in, const int* in_sizes, int n_in,
                              void* d_out, int out_size, void* d_ws, size_t ws_size,
                              hipStream_t stream) {
  const float* I    = (const float*)d_in[0];
  const float* DT   = (const float*)d_in[1];
  const float* Wrec = (const float*)d_in[2];
  const float* Win  = (const float*)d_in[3];
  const float* bv   = (const float*)d_in[4];
  const float* Av   = (const float*)d_in[5];
  const float* tauv = (const float*)d_in[6];
  float* out = (float*)d_out;
  ull* mbx = (ull*)d_ws;  // 16*2*8*512*8 B = 1 MB

  liquid_kernel<<<256, 512, 0, stream>>>(I, DT, Wrec, Win, bv, Av, tauv, mbx, out);
}